// Round 9
// baseline (260.484 us; speedup 1.0000x reference)
//
#include <hip/hip_runtime.h>
#include <hip/hip_bf16.h>

typedef unsigned short u16;
typedef unsigned int u32;
typedef short short8 __attribute__((ext_vector_type(8)));
typedef short short4v __attribute__((ext_vector_type(4)));
typedef float f32x4 __attribute__((ext_vector_type(4)));
typedef unsigned int u32x4 __attribute__((ext_vector_type(4)));

#define MFMA16(a, b, c) __builtin_amdgcn_mfma_f32_16x16x32_bf16((a), (b), (c), 0, 0, 0)

constexpr int kB = 4, kT = 2048, kC = 1024, kH = 16, kD = 64;
constexpr int kBT = kB * kT;                   // 8192
constexpr long kQKV = (long)kB * kH * kT * kD; // 8,388,608 elems per tensor
constexpr float kSC = 0.125f * 1.4426950408889634f;  // 1/sqrt(64) * log2(e)

__device__ inline u16 f2bf(float f) {
    __hip_bfloat16 h = __float2bfloat16(f);
    return *reinterpret_cast<u16*>(&h);
}
// pack two fp32 -> two truncated bf16 in one v_perm_b32
__device__ inline u32 pkbf_trunc(float lo, float hi) {
    return __builtin_amdgcn_perm(__builtin_bit_cast(u32, hi),
                                 __builtin_bit_cast(u32, lo), 0x07060302u);
}
// RNE pack via f2bf
__device__ inline u32 pkbf_rne(float lo, float hi) {
    return ((u32)f2bf(hi) << 16) | (u32)f2bf(lo);
}

// async global->LDS, 16B per lane. LDS dest must be wave-uniform base + lane*16.
__device__ inline void cp16(const u16* g, u16* l) {
    __builtin_amdgcn_global_load_lds(
        (const __attribute__((address_space(1))) unsigned int*)g,
        (__attribute__((address_space(3))) unsigned int*)l, 16, 0, 0);
}

// ---------------------------------------------------------------------------
// Kernel 0: cast x, Wk, Wq, Wv, Wp (fp32) -> bf16 in workspace.
// ---------------------------------------------------------------------------
__global__ __launch_bounds__(256) void cast_kernel(
    const float* __restrict__ x,  const float* __restrict__ Wk,
    const float* __restrict__ Wq, const float* __restrict__ Wv,
    const float* __restrict__ Wp,
    u16* __restrict__ xb, u16* __restrict__ wkb, u16* __restrict__ wqb,
    u16* __restrict__ wvb, u16* __restrict__ wpb)
{
    const long id = (long)blockIdx.x * 256 + threadIdx.x;  // float4 index
    const float* src;
    u16* dst;
    long off;
    if (id < 2097152) {            // x: 8M floats = 2M float4
        src = x; dst = xb; off = id;
    } else {
        const long w = (id - 2097152) >> 18;   // 262144 float4 per W
        off = (id - 2097152) & 262143;
        src = (w == 0) ? Wk : (w == 1) ? Wq : (w == 2) ? Wv : Wp;
        dst = (w == 0) ? wkb : (w == 1) ? wqb : (w == 2) ? wvb : wpb;
    }
    f32x4 v = *(const f32x4*)&src[off * 4];
    short4v s = {(short)f2bf(v[0]), (short)f2bf(v[1]),
                 (short)f2bf(v[2]), (short)f2bf(v[3])};
    *(short4v*)&dst[off * 4] = s;
}

// ===========================================================================
// v5 GEMM template: BM=128, BN=128, BK=64, 256 thr = 4 waves (2M x 2N),
// wave tile 64x64 (4m x 4n frags). LDS 64 KB -> TWO independent blocks/CU
// (the round-8 attn lesson: independent barrier domains beat single-domain
// pipelining at equal waves/SIMD). 4 phases per K-tile, counted vmcnt:
// per-tile staging units (thread-relative) Bna=2, A=4(aMa+aMb), Bnb=2,
// issued in that order; ph0 waits vmcnt(2) (drains Bna+A of tile t, leaves
// Bnb(t)); ph2 waits vmcnt(6) (drains Bnb(t), leaves tile t+1's 6). Never
// drains mid-loop. Chunk-XOR swizzled LDS (conflict-free b128).
// ===========================================================================

// ---------------------------------------------------------------------------
// Kernel 1 (fast): QKV projection, bf16 inputs, combined W [3072][1024]
// (wkb/wqb/wvb contiguous). Grid (64, 24) = 1536 blocks = 3 even rounds
// at 2 blocks/CU. z = n>>10: 0 -> K (B,H,T,D), 1 -> Q PRESCALED by kSC,
// 2 -> V^T (B,H,D,T)
// ---------------------------------------------------------------------------
__global__ __launch_bounds__(256, 2) void qkv_gemm_bf16(
    const u16* __restrict__ xb, const u16* __restrict__ wall,
    const float* __restrict__ bk, const float* __restrict__ bq,
    const float* __restrict__ bv,
    u16* __restrict__ kw, u16* __restrict__ qw, u16* __restrict__ vw)
{
    __shared__ __align__(16) u16 A2[2][128 * 64];   // 32 KB
    __shared__ __align__(16) u16 B2[2][128 * 64];   // 32 KB

    const int tid = threadIdx.x;      // 0..255
    const int lane = tid & 63;
    const int wid = tid >> 6;         // 0..3
    const int l15 = lane & 15;
    const int quad = lane >> 4;
    const int wr = wid & 1;           // M wave
    const int wc = wid >> 1;          // N wave 0..1
    const int m0 = blockIdx.x * 128;
    const int n0c = blockIdx.y * 128; // combined-N offset

    f32x4 zero = {0.f, 0.f, 0.f, 0.f};
    f32x4 acc[4][4];
#pragma unroll
    for (int i = 0; i < 4; ++i)
#pragma unroll
        for (int j = 0; j < 4; ++j) acc[i][j] = zero;

    // ---- staging maps: q in {0,1}; slot = q*256+tid; v = slot>>3 (0..63),
    // ch = slot&7. ra = ((v>>5)<<6)+(v&31) -> rows {0-31,64-95}; rb = ra+32.
    // LDS chunk c holds global chunk c^(row&7) (involution per row).
    const u16* aMaS[2]; const u16* aMbS[2];
    const u16* bNaS[2]; const u16* bNbS[2];
    int aMaD[2], aMbD[2], bNaD[2], bNbD[2];
#pragma unroll
    for (int q = 0; q < 2; ++q) {
        const int slot = q * 256 + tid;
        const int v = slot >> 3, ch = slot & 7;
        const int ra = ((v >> 5) << 6) + (v & 31);
        const int rb = ra + 32;
        aMaS[q] = xb + (long)(m0 + ra) * kC + ((ch ^ (ra & 7)) * 8);
        aMbS[q] = xb + (long)(m0 + rb) * kC + ((ch ^ (rb & 7)) * 8);
        aMaD[q] = ra * 64 + ch * 8;
        aMbD[q] = rb * 64 + ch * 8;
        bNaS[q] = wall + (long)(n0c + ra) * kC + ((ch ^ (ra & 7)) * 8);
        bNbS[q] = wall + (long)(n0c + rb) * kC + ((ch ^ (rb & 7)) * 8);
        bNaD[q] = ra * 64 + ch * 8;
        bNbD[q] = rb * 64 + ch * 8;
    }

    // ---- frag-read offsets (swizzled) ----
    int aOff[4][2], bOff[4][2];
#pragma unroll
    for (int i = 0; i < 4; ++i) {
        const int row = wr * 64 + i * 16 + l15;
#pragma unroll
        for (int k2 = 0; k2 < 2; ++k2)
            aOff[i][k2] = row * 64 + (((k2 * 4 + quad) ^ (row & 7)) * 8);
    }
#pragma unroll
    for (int j = 0; j < 4; ++j) {
        const int row = wc * 64 + j * 16 + l15;
#pragma unroll
        for (int k2 = 0; k2 < 2; ++k2)
            bOff[j][k2] = row * 64 + (((k2 * 4 + quad) ^ (row & 7)) * 8);
    }

    // ---- prologue: tile 0 in wait-accounting order Bna, aMa, aMb, Bnb ----
    cp16(bNaS[0], &B2[0][bNaD[0]]);
    cp16(bNaS[1], &B2[0][bNaD[1]]);
    cp16(aMaS[0], &A2[0][aMaD[0]]);
    cp16(aMaS[1], &A2[0][aMaD[1]]);
    cp16(aMbS[0], &A2[0][aMbD[0]]);
    cp16(aMbS[1], &A2[0][aMbD[1]]);
    cp16(bNbS[0], &B2[0][bNbD[0]]);
    cp16(bNbS[1], &B2[0][bNbD[1]]);

#pragma unroll 2
    for (int t = 0; t < 16; ++t) {
        const int c = t & 1;
        const u16* Ab = A2[c];
        const u16* Bb = B2[c];
        u16* An = A2[c ^ 1];
        u16* Bn = B2[c ^ 1];
        const long ko = (long)(t + 1) * 64;
        const bool pf = (t < 15);

        short8 amL[2][2], amH[2][2], bnL[2][2], bnH[2][2];

        // ---------------- phase 0: C[m01][n01] ----------------
        asm volatile("s_waitcnt vmcnt(2)" ::: "memory");   // Bna(t)+A(t) in
        __builtin_amdgcn_s_barrier();
        __builtin_amdgcn_sched_barrier(0);
#pragma unroll
        for (int i = 0; i < 2; ++i)
#pragma unroll
            for (int k2 = 0; k2 < 2; ++k2)
                amL[i][k2] = *(const short8*)&Ab[aOff[i][k2]];
#pragma unroll
        for (int j = 0; j < 2; ++j)
#pragma unroll
            for (int k2 = 0; k2 < 2; ++k2)
                bnL[j][k2] = *(const short8*)&Bb[bOff[j][k2]];
        if (pf) {
            cp16(bNaS[0] + ko, &Bn[bNaD[0]]);
            cp16(bNaS[1] + ko, &Bn[bNaD[1]]);
        }
        asm volatile("s_waitcnt lgkmcnt(0)" ::: "memory");
        __builtin_amdgcn_sched_barrier(0);
        __builtin_amdgcn_s_setprio(1);
#pragma unroll
        for (int i = 0; i < 2; ++i)
#pragma unroll
            for (int j = 0; j < 2; ++j) {
                acc[i][j] = MFMA16(amL[i][0], bnL[j][0], acc[i][j]);
                acc[i][j] = MFMA16(amL[i][1], bnL[j][1], acc[i][j]);
            }
        __builtin_amdgcn_s_setprio(0);

        // ---------------- phase 1: C[m23][n01] ----------------
#pragma unroll
        for (int i = 0; i < 2; ++i)
#pragma unroll
            for (int k2 = 0; k2 < 2; ++k2)
                amH[i][k2] = *(const short8*)&Ab[aOff[2 + i][k2]];
        if (pf) {
            cp16(aMaS[0] + ko, &An[aMaD[0]]);
            cp16(aMaS[1] + ko, &An[aMaD[1]]);
            cp16(aMbS[0] + ko, &An[aMbD[0]]);
            cp16(aMbS[1] + ko, &An[aMbD[1]]);
        }
        asm volatile("s_waitcnt lgkmcnt(0)" ::: "memory");
        __builtin_amdgcn_sched_barrier(0);
        __builtin_amdgcn_s_setprio(1);
#pragma unroll
        for (int i = 0; i < 2; ++i)
#pragma unroll
            for (int j = 0; j < 2; ++j) {
                acc[2 + i][j] = MFMA16(amH[i][0], bnL[j][0], acc[2 + i][j]);
                acc[2 + i][j] = MFMA16(amH[i][1], bnL[j][1], acc[2 + i][j]);
            }
        __builtin_amdgcn_s_setprio(0);

        // ---------------- phase 2: C[m01][n23] ----------------
        if (pf) {
            asm volatile("s_waitcnt vmcnt(6)" ::: "memory");  // Bnb(t) in
        } else {
            asm volatile("s_waitcnt vmcnt(0)" ::: "memory");
        }
        __builtin_amdgcn_s_barrier();
        __builtin_amdgcn_sched_barrier(0);
#pragma unroll
        for (int j = 0; j < 2; ++j)
#pragma unroll
            for (int k2 = 0; k2 < 2; ++k2)
                bnH[j][k2] = *(const short8*)&Bb[bOff[2 + j][k2]];
        if (pf) {
            cp16(bNbS[0] + ko, &Bn[bNbD[0]]);
            cp16(bNbS[1] + ko, &Bn[bNbD[1]]);
        }
        asm volatile("s_waitcnt lgkmcnt(0)" ::: "memory");
        __builtin_amdgcn_sched_barrier(0);
        __builtin_amdgcn_s_setprio(1);
#pragma unroll
        for (int i = 0; i < 2; ++i)
#pragma unroll
            for (int j = 0; j < 2; ++j) {
                acc[i][2 + j] = MFMA16(amL[i][0], bnH[j][0], acc[i][2 + j]);
                acc[i][2 + j] = MFMA16(amL[i][1], bnH[j][1], acc[i][2 + j]);
            }
        __builtin_amdgcn_s_setprio(0);

        // ---------------- phase 3: C[m23][n23] ----------------
        __builtin_amdgcn_s_setprio(1);
#pragma unroll
        for (int i = 0; i < 2; ++i)
#pragma unroll
            for (int j = 0; j < 2; ++j) {
                acc[2 + i][2 + j] = MFMA16(amH[i][0], bnH[j][0], acc[2 + i][2 + j]);
                acc[2 + i][2 + j] = MFMA16(amH[i][1], bnH[j][1], acc[2 + i][2 + j]);
            }
        __builtin_amdgcn_s_setprio(0);
    }

    // ---- epilogue ----
    const int z = (n0c >> 10);              // uniform per block (y/8)
    const float scale = (z == 1) ? kSC : 1.0f;
    const float* bias = (z == 0) ? bk : (z == 1) ? bq : bv;
#pragma unroll
    for (int j = 0; j < 4; ++j) {
        const int n = n0c + wc * 64 + j * 16 + l15;
        const int np = n & 1023;
        const float bias_f = bias[np];
        const int h = np >> 6, d = np & 63;
#pragma unroll
        for (int i = 0; i < 4; ++i) {
#pragma unroll
            for (int r = 0; r < 4; ++r) {
                const int m = m0 + wr * 64 + i * 16 + quad * 4 + r;
                const int b = m >> 11, tt = m & 2047;
                const float v = (acc[i][j][r] + bias_f) * scale;
                const int bh = b * kH + h;
                if (z == 2) {
                    vw[((long)bh * kD + d) * kT + tt] = f2bf(v);   // V^T
                } else {
                    u16* dst = (z == 0) ? kw : qw;
                    dst[((long)bh * kT + tt) * kD + d] = f2bf(v);  // (B,H,T,D)
                }
            }
        }
    }
}

// ---------------------------------------------------------------------------
// Kernel 1 (fallback): QKV projection from fp32 with in-kernel cvt staging.
// ---------------------------------------------------------------------------
__global__ __launch_bounds__(256) void qkv_gemm_kernel(
    const float* __restrict__ x,
    const float* __restrict__ Wk, const float* __restrict__ bk,
    const float* __restrict__ Wq, const float* __restrict__ bq,
    const float* __restrict__ Wv, const float* __restrict__ bv,
    u16* __restrict__ kw, u16* __restrict__ qw, u16* __restrict__ vw)
{
    __shared__ u16 As[128 * 32];
    __shared__ u16 Bs[128 * 32];
    const int tid = threadIdx.x;
    const int lane = tid & 63;
    const int wid = tid >> 6;
    const int l15 = lane & 15;
    const int quad = lane >> 4;
    const int m0 = blockIdx.x * 128;
    const int n0 = blockIdx.y * 128;
    const int z = blockIdx.z;

    const float* W = (z == 0) ? Wk : (z == 1) ? Wq : Wv;
    const float* bias = (z == 0) ? bk : (z == 1) ? bq : bv;

    f32x4 zero = {0.f, 0.f, 0.f, 0.f};
    f32x4 acc[4][4];
#pragma unroll
    for (int i = 0; i < 4; ++i)
#pragma unroll
        for (int j = 0; j < 4; ++j) acc[i][j] = zero;

    const int wm = (wid & 1) * 64;
    const int wn = (wid >> 1) * 64;
    const int row4 = tid >> 3;
    const int col4 = (tid & 7) * 4;

    for (int k0 = 0; k0 < kC; k0 += 32) {
#pragma unroll
        for (int p = 0; p < 4; ++p) {
            const int r = p * 32 + row4;
            f32x4 xa = *(const f32x4*)&x[(long)(m0 + r) * kC + k0 + col4];
            f32x4 wa = *(const f32x4*)&W[(long)(n0 + r) * kC + k0 + col4];
            short4v xs = {(short)f2bf(xa[0]), (short)f2bf(xa[1]),
                          (short)f2bf(xa[2]), (short)f2bf(xa[3])};
            short4v wsv = {(short)f2bf(wa[0]), (short)f2bf(wa[1]),
                           (short)f2bf(wa[2]), (short)f2bf(wa[3])};
            *(short4v*)&As[r * 32 + col4] = xs;
            *(short4v*)&Bs[r * 32 + col4] = wsv;
        }
        __syncthreads();
        short8 af[4], bfr[4];
#pragma unroll
        for (int mt = 0; mt < 4; ++mt)
            af[mt] = *(const short8*)&As[(wm + mt * 16 + l15) * 32 + quad * 8];
#pragma unroll
        for (int nt = 0; nt < 4; ++nt)
            bfr[nt] = *(const short8*)&Bs[(wn + nt * 16 + l15) * 32 + quad * 8];
#pragma unroll
        for (int mt = 0; mt < 4; ++mt)
#pragma unroll
            for (int nt = 0; nt < 4; ++nt)
                acc[mt][nt] = MFMA16(af[mt], bfr[nt], acc[mt][nt]);
        __syncthreads();
    }

    const float scale = (z == 1) ? kSC : 1.0f;
#pragma unroll
    for (int nt = 0; nt < 4; ++nt) {
        const int n = n0 + wn + nt * 16 + l15;
        const float bias_f = bias[n];
        const int h = n >> 6, d = n & 63;
#pragma unroll
        for (int mt = 0; mt < 4; ++mt) {
#pragma unroll
            for (int r = 0; r < 4; ++r) {
                const int m = m0 + wm + mt * 16 + quad * 4 + r;
                const int b = m >> 11, t = m & 2047;
                const float v = (acc[mt][nt][r] + bias_f) * scale;
                const int bh = b * kH + h;
                if (z == 2) {
                    vw[((long)bh * kD + d) * kT + t] = f2bf(v);
                } else {
                    u16* dst = (z == 0) ? kw : qw;
                    dst[((long)bh * kT + t) * kD + d] = f2bf(v);
                }
            }
        }
    }
}

// ---------------------------------------------------------------------------
// Kernel 2: transposed flash attention, causal, v8 (UNCHANGED from round 8).
// UNPAIRED 128-row q-blocks, grid 1024 = 4 blocks/CU (16 waves/CU),
// permlane in-register softmax (no Pb, LDS 32KB), longest-first p-perm,
// __syncthreads-only sync (provably race-free), depth-2 prefetch.
// Mask: sl > tl - (st-2p)*64. S^T = K.Q^T; O^T = V^T.P^T.
// ---------------------------------------------------------------------------
__global__ __launch_bounds__(256, 4) void attn_kernel(
    const u16* qw, const u16* kw, const u16* vw, u16* ow)
{
    __shared__ u16 Ks[2][64 * 64];   // [buf][s][d], swizzled, 8KB each
    __shared__ u16 VT[2][64 * 64];   // [buf][d][s], swizzled

    const int tid = threadIdx.x;     // 0..255
    const int lane = tid & 63;
    const int wid = tid >> 6;        // 0..3
    const int l15 = lane & 15;
    const int quad = lane >> 4;
    const int id = blockIdx.x;
    const int bh = id & 63;
    constexpr int pperm[16] = {15, 14, 13, 12, 0, 1, 2, 3,
                               11, 10, 9, 8, 4, 5, 6, 7};
    const int p = pperm[id >> 6];    // 0..15, balanced + longest-first
    const int p2 = 2 * p;
    const int n_st = p2 + 2;
    const int tw = p * 128 + wid * 32;             // this wave's 32 rows

    const float NEG = -1.0e30f;
    f32x4 zero = {0.f, 0.f, 0.f, 0.f};
    const short8 onesf = {(short)0x3F80, (short)0x3F80, (short)0x3F80, (short)0x3F80,
                          (short)0x3F80, (short)0x3F80, (short)0x3F80, (short)0x3F80};

    const int rl7 = l15 & 7;

    const u16* kbase = kw + (long)bh * kT * kD;        // K rows [t][d]
    const u16* vbase = vw + (long)bh * kD * kT;        // V^T rows [d][t]

    const u16* kp[2];
    const u16* vp[2];
    int sdst[2];
#pragma unroll
    for (int q = 0; q < 2; ++q) {
        const int slot = q * 256 + tid;
        const int row = slot >> 3;
        const int c = slot & 7;
        const int off = (c ^ (row & 7)) * 8;
        kp[q] = kbase + (long)row * kD + off;
        vp[q] = vbase + (long)row * kT + off;
        sdst[q] = slot * 8;
    }

    auto stage = [&](int buf, int st) {
        u16* kd = Ks[buf];
        u16* vd = VT[buf];
#pragma unroll
        for (int q = 0; q < 2; ++q) {
            cp16(kp[q] + (long)st * (64 * kD), kd + sdst[q]);
            cp16(vp[q] + st * 64,              vd + sdst[q]);
        }
    };

    // Q as MFMA B-operand: 2 row-groups of 16
    short8 qf[2][2];
#pragma unroll
    for (int g = 0; g < 2; ++g) {
        const u16* qp = qw + ((long)bh * kT + tw + g * 16 + l15) * kD;
        qf[g][0] = *(const short8*)&qp[quad * 8];
        qf[g][1] = *(const short8*)&qp[32 + quad * 8];
    }

    // prologue: tiles 0,1 -> bufs 0,1; one full-fence sync drains both
    stage(0, 0);
    stage(1, 1);
    __syncthreads();

    f32x4 oacc[4][2];
#pragma unroll
    for (int mo = 0; mo < 4; ++mo)
#pragma unroll
        for (int g = 0; g < 2; ++g) oacc[mo][g] = zero;
    f32x4 lsum[2] = {zero, zero};

    for (int st = 0; st < n_st; ++st) {
        const int cur = st & 1;
        const u16* K_ = Ks[cur];
        const u16* V_ = VT[cur];

        // S^T = K.Q^T : A = K rows (s), B = Q rows (t); kf reused for 2 g
        f32x4 sacc[4][2];
        __builtin_amdgcn_s_setprio(1);
#pragma unroll
        for (int ms = 0; ms < 4; ++ms) {
            const int row = ms * 16 + l15;
            short8 kf0 = *(const short8*)&K_[row * 64 + ((quad ^ rl7) * 8)];
            short8 kf1 = *(const short8*)&K_[row * 64 + (((4 + quad) ^ rl7) * 8)];
#pragma unroll
            for (int g = 0; g < 2; ++g) {
                sacc[ms][g] = MFMA16(kf0, qf[g][0], zero);
                sacc[ms][g] = MFMA16(kf1, qf[g][1], sacc[ms][g]);
            }
        }
        __builtin_amdgcn_s_setprio(0);

        // causal mask: tile st covers s = st*64 + sl; row t = p*128 + tl.
        const int dg = st - p2;
        if (dg >= 0) {
#pragma unroll
            for (int g = 0; g < 2; ++g) {
                const int off = wid * 32 + g * 16 + l15 - dg * 64;
#pragma unroll
                for (int ms = 0; ms < 4; ++ms)
#pragma unroll
                    for (int r = 0; r < 4; ++r)
                        if (ms * 16 + quad * 4 + r > off) sacc[ms][g][r] = NEG;
            }
        }

        // P = exp2(S) -> NATURAL-order bf16 B-fragments in-register.
        short8 pfr[2][2];
#pragma unroll
        for (int g = 0; g < 2; ++g) {
#pragma unroll
            for (int k2 = 0; k2 < 2; ++k2) {
                const int msA = k2 * 2, msB = k2 * 2 + 1;
                const float a0 = exp2f(sacc[msA][g][0]);
                const float a1 = exp2f(sacc[msA][g][1]);
                const float a2 = exp2f(sacc[msA][g][2]);
                const float a3 = exp2f(sacc[msA][g][3]);
                const float b0 = exp2f(sacc[msB][g][0]);
                const float b1 = exp2f(sacc[msB][g][1]);
                const float b2 = exp2f(sacc[msB][g][2]);
                const float b3 = exp2f(sacc[msB][g][3]);
                const u32 LA = pkbf_trunc(a0, a1), HA = pkbf_trunc(a2, a3);
                const u32 LB = pkbf_trunc(b0, b1), HB = pkbf_trunc(b2, b3);
                auto pL = __builtin_amdgcn_permlane32_swap(LA, LB, false, false);
                auto pH = __builtin_amdgcn_permlane32_swap(HA, HB, false, false);
                auto rL = __builtin_amdgcn_permlane16_swap(pL[0], pL[1], false, false);
                auto rH = __builtin_amdgcn_permlane16_swap(pH[0], pH[1], false, false);
                u32x4 w;
                w[0] = rL[0]; w[1] = rH[0]; w[2] = rL[1]; w[3] = rH[1];
                pfr[g][k2] = __builtin_bit_cast(short8, w);
            }
        }

        // row-sum via ones-MFMA (same fragments -> bit-consistent)
#pragma unroll
        for (int g = 0; g < 2; ++g) {
            lsum[g] = MFMA16(onesf, pfr[g][0], lsum[g]);
            lsum[g] = MFMA16(onesf, pfr[g][1], lsum[g]);
        }

        // O^T += V^T . P^T ; vf (conflict-free b128) reused for 2 g
        __builtin_amdgcn_s_setprio(1);
#pragma unroll
        for (int mo = 0; mo < 4; ++mo) {
            const int row = mo * 16 + l15;
            short8 vf0 = *(const short8*)&V_[row * 64 + ((quad ^ rl7) * 8)];
            short8 vf1 = *(const short8*)&V_[row * 64 + (((4 + quad) ^ rl7) * 8)];
#pragma unroll
            for (int g = 0; g < 2; ++g) {
                oacc[mo][g] = MFMA16(vf0, pfr[g][0], oacc[mo][g]);
                oacc[mo][g] = MFMA16(vf1, pfr[g][1], oacc[mo][g]);
            }
        }
        __builtin_amdgcn_s_setprio(0);

        // one full-fence sync per step, then prefetch st+2 into just-read buf
        if (st + 1 < n_st) {
            __syncthreads();
            if (st + 2 < n_st) stage(cur, st + 2);
        }
    }

    // epilogue: O[t][d] = oacc^T / l, packed uint2 stores
#pragma unroll
    for (int g = 0; g < 2; ++g) {
        const float inv = 1.0f / lsum[g][0];
        const int t = tw + g * 16 + l15;
        u16* op = ow + ((long)bh * kT + t) * kD;
#pragma unroll
        for (int mo = 0; mo < 4; ++mo) {
            uint2 ov;
            ov.x = pkbf_rne(oacc[mo][g][0] * inv, oacc[mo][g][1] * inv);
            ov.y = pkbf_rne(oacc[mo][g][2] * inv, oacc[mo][g][3] * inv);
            *(uint2*)&op[mo * 16 + quad * 4] = ov;
        }
    }
}

// ---------------------------------------------------------------------------
// Kernel 3 (fast): output projection, v5 template (BM=128, BN=128, 256 thr,
// 64 KB LDS -> 2 blocks/CU). BK=64 == head dim, K-tile t = head h=t;
// A-row stride per tile = kT*kD u16. Grid (64,8) = 512 = one even round.
// ---------------------------------------------------------------------------
__global__ __launch_bounds__(256, 2) void out_gemm_bf16(
    const u16* __restrict__ ob, const u16* __restrict__ wpb,
    const float* __restrict__ bp, float* __restrict__ out)
{
    __shared__ __align__(16) u16 A2[2][128 * 64];
    __shared__ __align__(16) u16 B2[2][128 * 64];

    const int tid = threadIdx.x;
    const int lane = tid & 63;
    const int wid = tid >> 6;
    const int l15 = lane & 15;
    const int quad = lane >> 4;
    const int wr = wid & 1;
    const int wc = wid >> 1;
    const int m0 = blockIdx.x * 128;
    const int n0 = blockIdx.y * 128;

    f32x4 zero = {0.f, 0.f, 0.f, 0.f};
    f32x4 acc[4][4];
#pragma unroll
    for (int i = 0; i < 4; ++i)
#pragma unroll
        for (int j = 0; j < 4; ++j) acc[i][j] = zero;

    // A source: o in (B,H,T,D); all 128 rows of a block share b.
    const u16* aMaS[2]; const u16* aMbS[2];
    const u16* bNaS[2]; const u16* bNbS[2];
    int aMaD[2], aMbD[2], bNaD[2], bNbD[2];
#pragma unroll
    for (int q = 0; q < 2; ++q) {
        const int slot = q * 256 + tid;
        const int v = slot >> 3, ch = slot & 7;
        const int ra = ((v >> 5) << 6) + (v & 31);
        const int rb = ra + 32;
        const int mA = m0 + ra, mB = m0 + rb;
        aMaS[q] = ob + (((long)(mA >> 11) * kH) * kT + (mA & 2047)) * kD
                  + ((ch ^ (ra & 7)) * 8);
        aMbS[q] = ob + (((long)(mB >> 11) * kH) * kT + (mB & 2047)) * kD
                  + ((ch ^ (rb & 7)) * 8);
        aMaD[q] = ra * 64 + ch * 8;
        aMbD[q] = rb * 64 + ch * 8;
        bNaS[q] = wpb + (long)(n0 + ra) * kC + ((ch ^ (ra & 7)) * 8);
        bNbS[q] = wpb + (long)(n0 + rb) * kC + ((ch ^ (rb & 7)) * 8);
        bNaD[q] = ra * 64 + ch * 8;
        bNbD[q] = rb * 64 + ch * 8;
    }

    int aOff[4][2], bOff[4][2];
#pragma unroll
    for (int i = 0; i < 4; ++i) {
        const int row = wr * 64 + i * 16 + l15;
#pragma unroll
        for (int k2 = 0; k2 < 2; ++k2)
            aOff[i][k2] = row * 64 + (((k2 * 4 + quad) ^ (row & 7)) * 8);
    }
#pragma unroll
    for (int j = 0; j < 4; ++j) {
        const int row = wc * 64 + j * 16 + l15;
#pragma unroll
        for (int k2 = 0; k2 < 2; ++k2)
            bOff[j][k2] = row * 64 + (((k2 * 4 + quad) ^ (row & 7)) * 8);
    }

    cp16(bNaS[0], &B2[0][bNaD[0]]);
    cp16(bNaS[1], &B2[0][bNaD[1]]);
    cp16(aMaS[0], &A2[0][aMaD[0]]);
    cp16(aMaS[1], &A2[0][aMaD[1]]);
    cp16(aMbS[0], &A2[0][aMbD[0]]);
    cp16(aMbS[1], &A2[0][aMbD[1]]);
    cp16(bNbS[0], &B2[0][bNbD[0]]);
    cp16(bNbS[1], &B2[0][bNbD[1]]);

#pragma unroll 2
    for (int t = 0; t < 16; ++t) {
        const int c = t & 1;
        const u16* Ab = A2[c];
        const u16* Bb = B2[c];
        u16* An = A2[c ^ 1];
        u16* Bn = B2[c ^ 1];
        const long koA = (long)(t + 1) * kT * kD;   // next head
        const long koB = (long)(t + 1) * 64;
        const bool pf = (t < 15);

        short8 amL[2][2], amH[2][2], bnL[2][2], bnH[2][2];

        // phase 0
        asm volatile("s_waitcnt vmcnt(2)" ::: "memory");
        __builtin_amdgcn_s_barrier();
        __builtin_amdgcn_sched_barrier(0);
#pragma unroll
        for (int i = 0; i < 2; ++i)
#pragma unroll
            for (int k2 = 0; k2 < 2; ++k2)
                amL[i][k2] = *(const short8*)&Ab[aOff[i][k2]];
#pragma unroll
        for (int j = 0; j < 2; ++j)
#pragma unroll
            for (int k2 = 0; k2 < 2; ++k2)
                bnL[j][k2] = *(const short8*)&Bb[bOff[j][k2]];
        if (pf) {
            cp16(bNaS[0] + koB, &Bn[bNaD[0]]);
            cp16(bNaS[1] + koB, &Bn[bNaD[1]]);
        }
        asm volatile("s_waitcnt lgkmcnt(0)" ::: "memory");
        __builtin_amdgcn_sched_barrier(0);
        __builtin_amdgcn_s_setprio(1);
#pragma unroll
        for (int i = 0; i < 2; ++i)
#pragma unroll
            for (int j = 0; j < 2; ++j) {
                acc[i][j] = MFMA16(amL[i][0], bnL[j][0], acc[i][j]);
                acc[i][j] = MFMA16(amL[i][1], bnL[j][1], acc[i][j]);
            }
        __builtin_amdgcn_s_setprio(0);

        // phase 1
#pragma unroll
        for (int i = 0; i < 2; ++i)
#pragma unroll
            for (int k2 = 0; k2 < 2; ++k2)
                amH[i][k2] = *(const short8*)&Ab[aOff[2 + i][k2]];
        if (pf) {
            cp16(aMaS[0] + koA, &An[aMaD[0]]);
            cp16(aMaS[1] + koA, &An[aMaD[1]]);
            cp16(aMbS[0] + koA, &An[aMbD[0]]);
            cp16(aMbS[1] + koA, &An[aMbD[1]]);
        }
        asm volatile("s_waitcnt lgkmcnt(0)" ::: "memory");
        __builtin_amdgcn_sched_barrier(0);
        __builtin_amdgcn_s_setprio(1);
#pragma unroll
        for (int i = 0; i < 2; ++i)
#pragma unroll
            for (int j = 0; j < 2; ++j) {
                acc[2 + i][j] = MFMA16(amH[i][0], bnL[j][0], acc[2 + i][j]);
                acc[2 + i][j] = MFMA16(amH[i][1], bnL[j][1], acc[2 + i][j]);
            }
        __builtin_amdgcn_s_setprio(0);

        // phase 2
        if (pf) {
            asm volatile("s_waitcnt vmcnt(6)" ::: "memory");
        } else {
            asm volatile("s_waitcnt vmcnt(0)" ::: "memory");
        }
        __builtin_amdgcn_s_barrier();
        __builtin_amdgcn_sched_barrier(0);
#pragma unroll
        for (int j = 0; j < 2; ++j)
#pragma unroll
            for (int k2 = 0; k2 < 2; ++k2)
                bnH[j][k2] = *(const short8*)&Bb[bOff[2 + j][k2]];
        if (pf) {
            cp16(bNbS[0] + koB, &Bn[bNbD[0]]);
            cp16(bNbS[1] + koB, &Bn[bNbD[1]]);
        }
        asm volatile("s_waitcnt lgkmcnt(0)" ::: "memory");
        __builtin_amdgcn_sched_barrier(0);
        __builtin_amdgcn_s_setprio(1);
#pragma unroll
        for (int i = 0; i < 2; ++i)
#pragma unroll
            for (int j = 0; j < 2; ++j) {
                acc[i][2 + j] = MFMA16(amL[i][0], bnH[j][0], acc[i][2 + j]);
                acc[i][2 + j] = MFMA16(amL[i][1], bnH[j][1], acc[i][2 + j]);
            }
        __builtin_amdgcn_s_setprio(0);

        // phase 3
        __builtin_amdgcn_s_setprio(1);
#pragma unroll
        for (int i = 0; i < 2; ++i)
#pragma unroll
            for (int j = 0; j < 2; ++j) {
                acc[2 + i][2 + j] = MFMA16(amH[i][0], bnH[j][0], acc[2 + i][2 + j]);
                acc[2 + i][2 + j] = MFMA16(amH[i][1], bnH[j][1], acc[2 + i][2 + j]);
            }
        __builtin_amdgcn_s_setprio(0);
    }

#pragma unroll
    for (int j = 0; j < 4; ++j) {
        const int n = n0 + wc * 64 + j * 16 + l15;
        const float bias_f = bp[n];
#pragma unroll
        for (int i = 0; i < 4; ++i) {
#pragma unroll
            for (int r = 0; r < 4; ++r) {
                const int m = m0 + wr * 64 + i * 16 + quad * 4 + r;
                out[(long)m * kC + n] = acc[i][j][r] + bias_f;
            }
        }
    }
}

// ---------------------------------------------------------------------------
// Kernel 3 (fallback): output projection from bf16 y + fp32 Wp.
// ---------------------------------------------------------------------------
__global__ __launch_bounds__(256) void out_gemm_kernel(
    const u16* __restrict__ ow, const float* __restrict__ Wp,
    const float* __restrict__ bp, float* __restrict__ out)
{
    __shared__ u16 As[128 * 32];
    __shared__ u16 Bs[128 * 32];
    const int tid = threadIdx.x;
    const int lane = tid & 63;
    const int wid = tid >> 6;
    const int l15 = lane & 15;
    const int quad = lane >> 4;
    const int m0 = blockIdx.x * 128;
    const int n0 = blockIdx.y * 128;

    f32x4 zero = {0.f, 0.f, 0.f, 0.f};
    f32x4 acc[4][4];
#pragma unroll
    for (int i = 0; i < 4; ++i)
#pragma unroll
        for (int j = 0; j < 4; ++j) acc[i][j] = zero;

    const int wm = (wid & 1) * 64;
    const int wn = (wid >> 1) * 64;

    const int r0 = tid >> 2;
    const int kkA = (tid & 3) * 8;
    const int r1 = r0 + 64;
    const int row4 = tid >> 3;
    const int col4 = (tid & 7) * 4;

    for (int k0 = 0; k0 < kC; k0 += 32) {
        {
            const int m = m0 + r0, b = m >> 11, t = m & 2047;
            const int kk = k0 + kkA, h = kk >> 6, d = kk & 63;
            *(short8*)&As[r0 * 32 + kkA] =
                *(const short8*)&ow[(((long)b * kH + h) * kT + t) * kD + d];
        }
        {
            const int m = m0 + r1, b = m >> 11, t = m & 2047;
            const int kk = k0 + kkA, h = kk >> 6, d = kk & 63;
            *(short8*)&As[r1 * 32 + kkA] =
                *(const short8*)&ow[(((long)b * kH + h) * kT + t) * kD + d];
        }
#pragma unroll
        for (int p = 0; p < 4; ++p) {
            const int r = p * 32 + row4;
            f32x4 wa = *(const f32x4*)&Wp[(long)(n0 + r) * kC + k0 + col4];
            short4v wsv = {(short)f2bf(wa[0]), (short)f2bf(wa[1]),
                           (short)f2bf(wa[2]), (short)f2bf(wa[3])};
            *(short4v*)&Bs[r * 32 + col4] = wsv;
        }
        __syncthreads();
        short8 af[4], bfr[4];
#pragma unroll
        for (int mt = 0; mt < 4; ++mt)
            af[mt] = *(const short8*)&As[(wm + mt * 16 + l15) * 32 + quad * 8];
#pragma unroll
        for (int nt = 0; nt < 4; ++nt)
            bfr[nt] = *(const short8*)&Bs[(wn + nt * 16 + l15) * 32 + quad * 8];
#pragma unroll
        for (int mt = 0; mt < 4; ++mt)
#pragma unroll
            for (int nt = 0; nt < 4; ++nt)
                acc[mt][nt] = MFMA16(af[mt], bfr[nt], acc[mt][nt]);
        __syncthreads();
    }

#pragma unroll
    for (int nt = 0; nt < 4; ++nt) {
        const int n = n0 + wn + nt * 16 + l15;
        const float bias_f = bp[n];
#pragma unroll
        for (int mt = 0; mt < 4; ++mt) {
#pragma unroll
            for (int r = 0; r < 4; ++r) {
                const int m = m0 + wm + mt * 16 + quad * 4 + r;
                out[(long)m * kC + n] = acc[mt][nt][r] + bias_f;
            }
        }
    }
}

// ---------------------------------------------------------------------------
extern "C" void kernel_launch(void* const* d_in, const int* in_sizes, int n_in,
                              void* d_out, int out_size, void* d_ws, size_t ws_size,
                              hipStream_t stream) {
    const float* x  = (const float*)d_in[0];
    const float* Wk = (const float*)d_in[1];
    const float* bk = (const float*)d_in[2];
    const float* Wq = (const float*)d_in[3];
    const float* bq = (const float*)d_in[4];
    const float* Wv = (const float*)d_in[5];
    const float* bv = (const float*)d_in[6];
    const float* Wp = (const float*)d_in[7];
    const float* bp = (const float*)d_in[8];
    float* out = (float*)d_out;

    u16* ws = (u16*)d_ws;
    const size_t kNeed = 72ull * 1024 * 1024;  // fast path footprint

    if (ws_size >= kNeed) {
        u16* k_ws = ws;
        u16* q_ws = ws + kQKV;
        u16* v_ws = ws + 2 * kQKV;
        u16* xb   = ws + 3 * kQKV;   // x bf16; o_ws reuses this region after qkv
        u16* o_ws = xb;
        u16* wkb  = ws + 4 * kQKV;   // wkb,wqb,wvb contiguous -> combined [3072][1024]
        u16* wqb  = wkb + (long)kC * kC;
        u16* wvb  = wqb + (long)kC * kC;
        u16* wpb  = wvb + (long)kC * kC;

        cast_kernel<<<12288, 256, 0, stream>>>(x, Wk, Wq, Wv, Wp,
                                               xb, wkb, wqb, wvb, wpb);
        qkv_gemm_bf16<<<dim3(kBT / 128, 24), 256, 0, stream>>>(
            xb, wkb, bk, bq, bv, k_ws, q_ws, v_ws);
        attn_kernel<<<1024, 256, 0, stream>>>(q_ws, k_ws, v_ws, o_ws);
        out_gemm_bf16<<<dim3(kBT / 128, kC / 128), 256, 0, stream>>>(
            o_ws, wpb, bp, out);
    } else {
        u16* k_ws = ws;
        u16* q_ws = ws + kQKV;
        u16* v_ws = ws + 2 * kQKV;
        u16* o_ws = q_ws;  // o aliases q (per-block read-then-write)

        qkv_gemm_kernel<<<dim3(kBT / 128, kC / 128, 3), 256, 0, stream>>>(
            x, Wk, bk, Wq, bq, Wv, bv, k_ws, q_ws, v_ws);
        attn_kernel<<<1024, 256, 0, stream>>>(q_ws, k_ws, v_ws, o_ws);
        out_gemm_kernel<<<dim3(kBT / 128, kC / 128), 256, 0, stream>>>(
            o_ws, Wp, bp, out);
    }
}

// Round 10
// 246.936 us; speedup vs baseline: 1.0549x; 1.0549x over previous
//
#include <hip/hip_runtime.h>
#include <hip/hip_bf16.h>

typedef unsigned short u16;
typedef unsigned int u32;
typedef short short8 __attribute__((ext_vector_type(8)));
typedef short short4v __attribute__((ext_vector_type(4)));
typedef float f32x4 __attribute__((ext_vector_type(4)));
typedef unsigned int u32x4 __attribute__((ext_vector_type(4)));

#define MFMA16(a, b, c) __builtin_amdgcn_mfma_f32_16x16x32_bf16((a), (b), (c), 0, 0, 0)

constexpr int kB = 4, kT = 2048, kC = 1024, kH = 16, kD = 64;
constexpr int kBT = kB * kT;                   // 8192
constexpr long kQKV = (long)kB * kH * kT * kD; // 8,388,608 elems per tensor
constexpr float kSC = 0.125f * 1.4426950408889634f;  // 1/sqrt(64) * log2(e)

__device__ inline u16 f2bf(float f) {
    __hip_bfloat16 h = __float2bfloat16(f);
    return *reinterpret_cast<u16*>(&h);
}
// pack two fp32 -> two truncated bf16 in one v_perm_b32
__device__ inline u32 pkbf_trunc(float lo, float hi) {
    return __builtin_amdgcn_perm(__builtin_bit_cast(u32, hi),
                                 __builtin_bit_cast(u32, lo), 0x07060302u);
}
// RNE pack via f2bf
__device__ inline u32 pkbf_rne(float lo, float hi) {
    return ((u32)f2bf(hi) << 16) | (u32)f2bf(lo);
}

// async global->LDS, 16B per lane. LDS dest must be wave-uniform base + lane*16.
__device__ inline void cp16(const u16* g, u16* l) {
    __builtin_amdgcn_global_load_lds(
        (const __attribute__((address_space(1))) unsigned int*)g,
        (__attribute__((address_space(3))) unsigned int*)l, 16, 0, 0);
}

// ---------------------------------------------------------------------------
// Kernel 0: cast x, Wk, Wq, Wv, Wp (fp32) -> bf16 in workspace.
// ---------------------------------------------------------------------------
__global__ __launch_bounds__(256) void cast_kernel(
    const float* __restrict__ x,  const float* __restrict__ Wk,
    const float* __restrict__ Wq, const float* __restrict__ Wv,
    const float* __restrict__ Wp,
    u16* __restrict__ xb, u16* __restrict__ wkb, u16* __restrict__ wqb,
    u16* __restrict__ wvb, u16* __restrict__ wpb)
{
    const long id = (long)blockIdx.x * 256 + threadIdx.x;  // float4 index
    const float* src;
    u16* dst;
    long off;
    if (id < 2097152) {            // x: 8M floats = 2M float4
        src = x; dst = xb; off = id;
    } else {
        const long w = (id - 2097152) >> 18;   // 262144 float4 per W
        off = (id - 2097152) & 262143;
        src = (w == 0) ? Wk : (w == 1) ? Wq : (w == 2) ? Wv : Wp;
        dst = (w == 0) ? wkb : (w == 1) ? wqb : (w == 2) ? wvb : wpb;
    }
    f32x4 v = *(const f32x4*)&src[off * 4];
    short4v s = {(short)f2bf(v[0]), (short)f2bf(v[1]),
                 (short)f2bf(v[2]), (short)f2bf(v[3])};
    *(short4v*)&dst[off * 4] = s;
}

// ===========================================================================
// v6 GEMM template: BM=128, BN=128, BK=64, 512 thr = 8 waves (2M x 4N),
// wave tile 64x32 (4m x 2n frags, 16 MFMA + 12 ds_read_b128 per tile).
// LDS = 2buf x (128+128) x 64 x 2B = 64 KB -> 2 blocks/CU = 16 waves/CU =
// 4 waves/SIMD (the round-8 attn lesson: 2->4 waves/SIMD was the lever; in
// round 9 I only reshuffled blocks at constant 8 waves/CU -> no gain).
// Sync = attn-v8's PROVEN race-free scheme, one __syncthreads per tile:
//   prologue: stage(buf0,t0); stage(buf1,t1); __syncthreads();
//   tile t:   read frags(buf c) -> 16 MFMA -> __syncthreads()
//             -> stage(c, t+2) into the just-read buffer.
// Tile t+1's DMA (issued end of tile t-1) is drained by the sync at end of
// tile t (a full tile of compute lead); overwrite of buf c strictly follows
// the sync at which all reads of it completed. No hand-counted vmcnt (the
// round-7 lesson: per-wave vmcnt gives no cross-wave visibility).
// Chunk-XOR swizzled LDS (conflict-free ds_read_b128).
// ===========================================================================

// ---------------------------------------------------------------------------
// Kernel 1 (fast): QKV projection, bf16 inputs, combined W [3072][1024]
// (wkb/wqb/wvb contiguous). Grid (64, 24) = 1536 blocks = 3 even rounds at
// 2 blocks/CU. z = n>>10: 0 -> K (B,H,T,D), 1 -> Q PRESCALED by kSC,
// 2 -> V^T (B,H,D,T)
// ---------------------------------------------------------------------------
__global__ __launch_bounds__(512, 4) void qkv_gemm_bf16(
    const u16* __restrict__ xb, const u16* __restrict__ wall,
    const float* __restrict__ bk, const float* __restrict__ bq,
    const float* __restrict__ bv,
    u16* __restrict__ kw, u16* __restrict__ qw, u16* __restrict__ vw)
{
    __shared__ __align__(16) u16 A2[2][128 * 64];   // 32 KB
    __shared__ __align__(16) u16 B2[2][128 * 64];   // 32 KB

    const int tid = threadIdx.x;      // 0..511
    const int lane = tid & 63;
    const int wid = tid >> 6;         // 0..7
    const int l15 = lane & 15;
    const int quad = lane >> 4;
    const int wr = wid & 1;           // M wave (64 rows)
    const int wc = wid >> 1;          // N wave 0..3 (32 cols)
    const int m0 = blockIdx.x * 128;
    const int n0c = blockIdx.y * 128; // combined-N offset

    f32x4 zero = {0.f, 0.f, 0.f, 0.f};
    f32x4 acc[4][2];
#pragma unroll
    for (int i = 0; i < 4; ++i)
#pragma unroll
        for (int j = 0; j < 2; ++j) acc[i][j] = zero;

    // ---- staging maps: slot = q*512 + tid (q=0,1); row = slot>>3 (0..127),
    // ch = slot&7. LDS chunk c holds global chunk c^(row&7).
    const u16* aS[2]; const u16* bS[2];
    int sD[2];
#pragma unroll
    for (int q = 0; q < 2; ++q) {
        const int slot = q * 512 + tid;
        const int row = slot >> 3, ch = slot & 7;
        aS[q] = xb + (long)(m0 + row) * kC + ((ch ^ (row & 7)) * 8);
        bS[q] = wall + (long)(n0c + row) * kC + ((ch ^ (row & 7)) * 8);
        sD[q] = row * 64 + ch * 8;
    }

    auto stage = [&](int buf, int t) {
        const long ko = (long)t * 64;
#pragma unroll
        for (int q = 0; q < 2; ++q) {
            cp16(aS[q] + ko, &A2[buf][sD[q]]);
            cp16(bS[q] + ko, &B2[buf][sD[q]]);
        }
    };

    // ---- frag-read offsets (swizzled) ----
    int aOff[4][2], bOff[2][2];
#pragma unroll
    for (int i = 0; i < 4; ++i) {
        const int row = wr * 64 + i * 16 + l15;
#pragma unroll
        for (int k2 = 0; k2 < 2; ++k2)
            aOff[i][k2] = row * 64 + (((k2 * 4 + quad) ^ (row & 7)) * 8);
    }
#pragma unroll
    for (int j = 0; j < 2; ++j) {
        const int row = wc * 32 + j * 16 + l15;
#pragma unroll
        for (int k2 = 0; k2 < 2; ++k2)
            bOff[j][k2] = row * 64 + (((k2 * 4 + quad) ^ (row & 7)) * 8);
    }

    // ---- prologue: tiles 0,1 -> bufs 0,1; one full-fence sync ----
    stage(0, 0);
    stage(1, 1);
    __syncthreads();

    for (int t = 0; t < 16; ++t) {
        const int c = t & 1;
        const u16* Ab = A2[c];
        const u16* Bb = B2[c];

        short8 am[4][2], bn[2][2];
#pragma unroll
        for (int i = 0; i < 4; ++i)
#pragma unroll
            for (int k2 = 0; k2 < 2; ++k2)
                am[i][k2] = *(const short8*)&Ab[aOff[i][k2]];
#pragma unroll
        for (int j = 0; j < 2; ++j)
#pragma unroll
            for (int k2 = 0; k2 < 2; ++k2)
                bn[j][k2] = *(const short8*)&Bb[bOff[j][k2]];

        __builtin_amdgcn_s_setprio(1);
#pragma unroll
        for (int i = 0; i < 4; ++i)
#pragma unroll
            for (int j = 0; j < 2; ++j) {
                acc[i][j] = MFMA16(am[i][0], bn[j][0], acc[i][j]);
                acc[i][j] = MFMA16(am[i][1], bn[j][1], acc[i][j]);
            }
        __builtin_amdgcn_s_setprio(0);

        // one full-fence sync per tile; then prefetch t+2 into just-read buf
        if (t + 1 < 16) {
            __syncthreads();
            if (t + 2 < 16) stage(c, t + 2);
        }
    }

    // ---- epilogue ----
    const int z = (n0c >> 10);              // uniform per block (y/8)
    const float scale = (z == 1) ? kSC : 1.0f;
    const float* bias = (z == 0) ? bk : (z == 1) ? bq : bv;
#pragma unroll
    for (int j = 0; j < 2; ++j) {
        const int n = n0c + wc * 32 + j * 16 + l15;
        const int np = n & 1023;
        const float bias_f = bias[np];
        const int h = np >> 6, d = np & 63;
#pragma unroll
        for (int i = 0; i < 4; ++i) {
#pragma unroll
            for (int r = 0; r < 4; ++r) {
                const int m = m0 + wr * 64 + i * 16 + quad * 4 + r;
                const int b = m >> 11, tt = m & 2047;
                const float v = (acc[i][j][r] + bias_f) * scale;
                const int bh = b * kH + h;
                if (z == 2) {
                    vw[((long)bh * kD + d) * kT + tt] = f2bf(v);   // V^T
                } else {
                    u16* dst = (z == 0) ? kw : qw;
                    dst[((long)bh * kT + tt) * kD + d] = f2bf(v);  // (B,H,T,D)
                }
            }
        }
    }
}

// ---------------------------------------------------------------------------
// Kernel 1 (fallback): QKV projection from fp32 with in-kernel cvt staging.
// ---------------------------------------------------------------------------
__global__ __launch_bounds__(256) void qkv_gemm_kernel(
    const float* __restrict__ x,
    const float* __restrict__ Wk, const float* __restrict__ bk,
    const float* __restrict__ Wq, const float* __restrict__ bq,
    const float* __restrict__ Wv, const float* __restrict__ bv,
    u16* __restrict__ kw, u16* __restrict__ qw, u16* __restrict__ vw)
{
    __shared__ u16 As[128 * 32];
    __shared__ u16 Bs[128 * 32];
    const int tid = threadIdx.x;
    const int lane = tid & 63;
    const int wid = tid >> 6;
    const int l15 = lane & 15;
    const int quad = lane >> 4;
    const int m0 = blockIdx.x * 128;
    const int n0 = blockIdx.y * 128;
    const int z = blockIdx.z;

    const float* W = (z == 0) ? Wk : (z == 1) ? Wq : Wv;
    const float* bias = (z == 0) ? bk : (z == 1) ? bq : bv;

    f32x4 zero = {0.f, 0.f, 0.f, 0.f};
    f32x4 acc[4][4];
#pragma unroll
    for (int i = 0; i < 4; ++i)
#pragma unroll
        for (int j = 0; j < 4; ++j) acc[i][j] = zero;

    const int wm = (wid & 1) * 64;
    const int wn = (wid >> 1) * 64;
    const int row4 = tid >> 3;
    const int col4 = (tid & 7) * 4;

    for (int k0 = 0; k0 < kC; k0 += 32) {
#pragma unroll
        for (int p = 0; p < 4; ++p) {
            const int r = p * 32 + row4;
            f32x4 xa = *(const f32x4*)&x[(long)(m0 + r) * kC + k0 + col4];
            f32x4 wa = *(const f32x4*)&W[(long)(n0 + r) * kC + k0 + col4];
            short4v xs = {(short)f2bf(xa[0]), (short)f2bf(xa[1]),
                          (short)f2bf(xa[2]), (short)f2bf(xa[3])};
            short4v wsv = {(short)f2bf(wa[0]), (short)f2bf(wa[1]),
                           (short)f2bf(wa[2]), (short)f2bf(wa[3])};
            *(short4v*)&As[r * 32 + col4] = xs;
            *(short4v*)&Bs[r * 32 + col4] = wsv;
        }
        __syncthreads();
        short8 af[4], bfr[4];
#pragma unroll
        for (int mt = 0; mt < 4; ++mt)
            af[mt] = *(const short8*)&As[(wm + mt * 16 + l15) * 32 + quad * 8];
#pragma unroll
        for (int nt = 0; nt < 4; ++nt)
            bfr[nt] = *(const short8*)&Bs[(wn + nt * 16 + l15) * 32 + quad * 8];
#pragma unroll
        for (int mt = 0; mt < 4; ++mt)
#pragma unroll
            for (int nt = 0; nt < 4; ++nt)
                acc[mt][nt] = MFMA16(af[mt], bfr[nt], acc[mt][nt]);
        __syncthreads();
    }

    const float scale = (z == 1) ? kSC : 1.0f;
#pragma unroll
    for (int nt = 0; nt < 4; ++nt) {
        const int n = n0 + wn + nt * 16 + l15;
        const float bias_f = bias[n];
        const int h = n >> 6, d = n & 63;
#pragma unroll
        for (int mt = 0; mt < 4; ++mt) {
#pragma unroll
            for (int r = 0; r < 4; ++r) {
                const int m = m0 + wm + mt * 16 + quad * 4 + r;
                const int b = m >> 11, t = m & 2047;
                const float v = (acc[mt][nt][r] + bias_f) * scale;
                const int bh = b * kH + h;
                if (z == 2) {
                    vw[((long)bh * kD + d) * kT + t] = f2bf(v);
                } else {
                    u16* dst = (z == 0) ? kw : qw;
                    dst[((long)bh * kT + t) * kD + d] = f2bf(v);
                }
            }
        }
    }
}

// ---------------------------------------------------------------------------
// Kernel 2: transposed flash attention, causal, v8 (UNCHANGED; passing).
// UNPAIRED 128-row q-blocks, grid 1024 = 4 blocks/CU (16 waves/CU),
// permlane in-register softmax (no Pb, LDS 32KB), longest-first p-perm,
// __syncthreads-only sync (provably race-free), depth-2 prefetch.
// Mask: sl > tl - (st-2p)*64. S^T = K.Q^T; O^T = V^T.P^T.
// ---------------------------------------------------------------------------
__global__ __launch_bounds__(256, 4) void attn_kernel(
    const u16* qw, const u16* kw, const u16* vw, u16* ow)
{
    __shared__ u16 Ks[2][64 * 64];   // [buf][s][d], swizzled, 8KB each
    __shared__ u16 VT[2][64 * 64];   // [buf][d][s], swizzled

    const int tid = threadIdx.x;     // 0..255
    const int lane = tid & 63;
    const int wid = tid >> 6;        // 0..3
    const int l15 = lane & 15;
    const int quad = lane >> 4;
    const int id = blockIdx.x;
    const int bh = id & 63;
    constexpr int pperm[16] = {15, 14, 13, 12, 0, 1, 2, 3,
                               11, 10, 9, 8, 4, 5, 6, 7};
    const int p = pperm[id >> 6];    // 0..15, balanced + longest-first
    const int p2 = 2 * p;
    const int n_st = p2 + 2;
    const int tw = p * 128 + wid * 32;             // this wave's 32 rows

    const float NEG = -1.0e30f;
    f32x4 zero = {0.f, 0.f, 0.f, 0.f};
    const short8 onesf = {(short)0x3F80, (short)0x3F80, (short)0x3F80, (short)0x3F80,
                          (short)0x3F80, (short)0x3F80, (short)0x3F80, (short)0x3F80};

    const int rl7 = l15 & 7;

    const u16* kbase = kw + (long)bh * kT * kD;        // K rows [t][d]
    const u16* vbase = vw + (long)bh * kD * kT;        // V^T rows [d][t]

    const u16* kp[2];
    const u16* vp[2];
    int sdst[2];
#pragma unroll
    for (int q = 0; q < 2; ++q) {
        const int slot = q * 256 + tid;
        const int row = slot >> 3;
        const int c = slot & 7;
        const int off = (c ^ (row & 7)) * 8;
        kp[q] = kbase + (long)row * kD + off;
        vp[q] = vbase + (long)row * kT + off;
        sdst[q] = slot * 8;
    }

    auto stage = [&](int buf, int st) {
        u16* kd = Ks[buf];
        u16* vd = VT[buf];
#pragma unroll
        for (int q = 0; q < 2; ++q) {
            cp16(kp[q] + (long)st * (64 * kD), kd + sdst[q]);
            cp16(vp[q] + st * 64,              vd + sdst[q]);
        }
    };

    // Q as MFMA B-operand: 2 row-groups of 16
    short8 qf[2][2];
#pragma unroll
    for (int g = 0; g < 2; ++g) {
        const u16* qp = qw + ((long)bh * kT + tw + g * 16 + l15) * kD;
        qf[g][0] = *(const short8*)&qp[quad * 8];
        qf[g][1] = *(const short8*)&qp[32 + quad * 8];
    }

    // prologue: tiles 0,1 -> bufs 0,1; one full-fence sync drains both
    stage(0, 0);
    stage(1, 1);
    __syncthreads();

    f32x4 oacc[4][2];
#pragma unroll
    for (int mo = 0; mo < 4; ++mo)
#pragma unroll
        for (int g = 0; g < 2; ++g) oacc[mo][g] = zero;
    f32x4 lsum[2] = {zero, zero};

    for (int st = 0; st < n_st; ++st) {
        const int cur = st & 1;
        const u16* K_ = Ks[cur];
        const u16* V_ = VT[cur];

        // S^T = K.Q^T : A = K rows (s), B = Q rows (t); kf reused for 2 g
        f32x4 sacc[4][2];
        __builtin_amdgcn_s_setprio(1);
#pragma unroll
        for (int ms = 0; ms < 4; ++ms) {
            const int row = ms * 16 + l15;
            short8 kf0 = *(const short8*)&K_[row * 64 + ((quad ^ rl7) * 8)];
            short8 kf1 = *(const short8*)&K_[row * 64 + (((4 + quad) ^ rl7) * 8)];
#pragma unroll
            for (int g = 0; g < 2; ++g) {
                sacc[ms][g] = MFMA16(kf0, qf[g][0], zero);
                sacc[ms][g] = MFMA16(kf1, qf[g][1], sacc[ms][g]);
            }
        }
        __builtin_amdgcn_s_setprio(0);

        // causal mask: tile st covers s = st*64 + sl; row t = p*128 + tl.
        const int dg = st - p2;
        if (dg >= 0) {
#pragma unroll
            for (int g = 0; g < 2; ++g) {
                const int off = wid * 32 + g * 16 + l15 - dg * 64;
#pragma unroll
                for (int ms = 0; ms < 4; ++ms)
#pragma unroll
                    for (int r = 0; r < 4; ++r)
                        if (ms * 16 + quad * 4 + r > off) sacc[ms][g][r] = NEG;
            }
        }

        // P = exp2(S) -> NATURAL-order bf16 B-fragments in-register.
        short8 pfr[2][2];
#pragma unroll
        for (int g = 0; g < 2; ++g) {
#pragma unroll
            for (int k2 = 0; k2 < 2; ++k2) {
                const int msA = k2 * 2, msB = k2 * 2 + 1;
                const float a0 = exp2f(sacc[msA][g][0]);
                const float a1 = exp2f(sacc[msA][g][1]);
                const float a2 = exp2f(sacc[msA][g][2]);
                const float a3 = exp2f(sacc[msA][g][3]);
                const float b0 = exp2f(sacc[msB][g][0]);
                const float b1 = exp2f(sacc[msB][g][1]);
                const float b2 = exp2f(sacc[msB][g][2]);
                const float b3 = exp2f(sacc[msB][g][3]);
                const u32 LA = pkbf_trunc(a0, a1), HA = pkbf_trunc(a2, a3);
                const u32 LB = pkbf_trunc(b0, b1), HB = pkbf_trunc(b2, b3);
                auto pL = __builtin_amdgcn_permlane32_swap(LA, LB, false, false);
                auto pH = __builtin_amdgcn_permlane32_swap(HA, HB, false, false);
                auto rL = __builtin_amdgcn_permlane16_swap(pL[0], pL[1], false, false);
                auto rH = __builtin_amdgcn_permlane16_swap(pH[0], pH[1], false, false);
                u32x4 w;
                w[0] = rL[0]; w[1] = rH[0]; w[2] = rL[1]; w[3] = rH[1];
                pfr[g][k2] = __builtin_bit_cast(short8, w);
            }
        }

        // row-sum via ones-MFMA (same fragments -> bit-consistent)
#pragma unroll
        for (int g = 0; g < 2; ++g) {
            lsum[g] = MFMA16(onesf, pfr[g][0], lsum[g]);
            lsum[g] = MFMA16(onesf, pfr[g][1], lsum[g]);
        }

        // O^T += V^T . P^T ; vf (conflict-free b128) reused for 2 g
        __builtin_amdgcn_s_setprio(1);
#pragma unroll
        for (int mo = 0; mo < 4; ++mo) {
            const int row = mo * 16 + l15;
            short8 vf0 = *(const short8*)&V_[row * 64 + ((quad ^ rl7) * 8)];
            short8 vf1 = *(const short8*)&V_[row * 64 + (((4 + quad) ^ rl7) * 8)];
#pragma unroll
            for (int g = 0; g < 2; ++g) {
                oacc[mo][g] = MFMA16(vf0, pfr[g][0], oacc[mo][g]);
                oacc[mo][g] = MFMA16(vf1, pfr[g][1], oacc[mo][g]);
            }
        }
        __builtin_amdgcn_s_setprio(0);

        // one full-fence sync per step, then prefetch st+2 into just-read buf
        if (st + 1 < n_st) {
            __syncthreads();
            if (st + 2 < n_st) stage(cur, st + 2);
        }
    }

    // epilogue: O[t][d] = oacc^T / l, packed uint2 stores
#pragma unroll
    for (int g = 0; g < 2; ++g) {
        const float inv = 1.0f / lsum[g][0];
        const int t = tw + g * 16 + l15;
        u16* op = ow + ((long)bh * kT + t) * kD;
#pragma unroll
        for (int mo = 0; mo < 4; ++mo) {
            uint2 ov;
            ov.x = pkbf_rne(oacc[mo][g][0] * inv, oacc[mo][g][1] * inv);
            ov.y = pkbf_rne(oacc[mo][g][2] * inv, oacc[mo][g][3] * inv);
            *(uint2*)&op[mo * 16 + quad * 4] = ov;
        }
    }
}

// ---------------------------------------------------------------------------
// Kernel 3 (fast): output projection, v6 template (BM=128, BN=128, BK=64,
// 512 thr, 64 KB LDS -> 2 blocks/CU = 4 waves/SIMD, syncthreads-only).
// BK=64 == head dim, K-tile t = head h=t; A-row stride/tile = kT*kD u16.
// Grid (64,8) = 512 = one even round at 2 blocks/CU.
// ---------------------------------------------------------------------------
__global__ __launch_bounds__(512, 4) void out_gemm_bf16(
    const u16* __restrict__ ob, const u16* __restrict__ wpb,
    const float* __restrict__ bp, float* __restrict__ out)
{
    __shared__ __align__(16) u16 A2[2][128 * 64];
    __shared__ __align__(16) u16 B2[2][128 * 64];

    const int tid = threadIdx.x;
    const int lane = tid & 63;
    const int wid = tid >> 6;
    const int l15 = lane & 15;
    const int quad = lane >> 4;
    const int wr = wid & 1;
    const int wc = wid >> 1;          // 0..3
    const int m0 = blockIdx.x * 128;
    const int n0 = blockIdx.y * 128;

    f32x4 zero = {0.f, 0.f, 0.f, 0.f};
    f32x4 acc[4][2];
#pragma unroll
    for (int i = 0; i < 4; ++i)
#pragma unroll
        for (int j = 0; j < 2; ++j) acc[i][j] = zero;

    // A source: o in (B,H,T,D); all 128 rows of a block share b.
    const u16* aS[2]; const u16* bS[2];
    int sD[2];
#pragma unroll
    for (int q = 0; q < 2; ++q) {
        const int slot = q * 512 + tid;
        const int row = slot >> 3, ch = slot & 7;
        const int m = m0 + row, b = m >> 11, trow = m & 2047;
        aS[q] = ob + (((long)b * kH) * kT + trow) * kD + ((ch ^ (row & 7)) * 8);
        bS[q] = wpb + (long)(n0 + row) * kC + ((ch ^ (row & 7)) * 8);
        sD[q] = row * 64 + ch * 8;
    }

    auto stage = [&](int buf, int t) {
        const long koA = (long)t * kT * kD;   // next head
        const long koB = (long)t * 64;
#pragma unroll
        for (int q = 0; q < 2; ++q) {
            cp16(aS[q] + koA, &A2[buf][sD[q]]);
            cp16(bS[q] + koB, &B2[buf][sD[q]]);
        }
    };

    int aOff[4][2], bOff[2][2];
#pragma unroll
    for (int i = 0; i < 4; ++i) {
        const int row = wr * 64 + i * 16 + l15;
#pragma unroll
        for (int k2 = 0; k2 < 2; ++k2)
            aOff[i][k2] = row * 64 + (((k2 * 4 + quad) ^ (row & 7)) * 8);
    }
#pragma unroll
    for (int j = 0; j < 2; ++j) {
        const int row = wc * 32 + j * 16 + l15;
#pragma unroll
        for (int k2 = 0; k2 < 2; ++k2)
            bOff[j][k2] = row * 64 + (((k2 * 4 + quad) ^ (row & 7)) * 8);
    }

    stage(0, 0);
    stage(1, 1);
    __syncthreads();

    for (int t = 0; t < 16; ++t) {
        const int c = t & 1;
        const u16* Ab = A2[c];
        const u16* Bb = B2[c];

        short8 am[4][2], bn[2][2];
#pragma unroll
        for (int i = 0; i < 4; ++i)
#pragma unroll
            for (int k2 = 0; k2 < 2; ++k2)
                am[i][k2] = *(const short8*)&Ab[aOff[i][k2]];
#pragma unroll
        for (int j = 0; j < 2; ++j)
#pragma unroll
            for (int k2 = 0; k2 < 2; ++k2)
                bn[j][k2] = *(const short8*)&Bb[bOff[j][k2]];

        __builtin_amdgcn_s_setprio(1);
#pragma unroll
        for (int i = 0; i < 4; ++i)
#pragma unroll
            for (int j = 0; j < 2; ++j) {
                acc[i][j] = MFMA16(am[i][0], bn[j][0], acc[i][j]);
                acc[i][j] = MFMA16(am[i][1], bn[j][1], acc[i][j]);
            }
        __builtin_amdgcn_s_setprio(0);

        if (t + 1 < 16) {
            __syncthreads();
            if (t + 2 < 16) stage(c, t + 2);
        }
    }

#pragma unroll
    for (int j = 0; j < 2; ++j) {
        const int n = n0 + wc * 32 + j * 16 + l15;
        const float bias_f = bp[n];
#pragma unroll
        for (int i = 0; i < 4; ++i) {
#pragma unroll
            for (int r = 0; r < 4; ++r) {
                const int m = m0 + wr * 64 + i * 16 + quad * 4 + r;
                out[(long)m * kC + n] = acc[i][j][r] + bias_f;
            }
        }
    }
}

// ---------------------------------------------------------------------------
// Kernel 3 (fallback): output projection from bf16 y + fp32 Wp.
// ---------------------------------------------------------------------------
__global__ __launch_bounds__(256) void out_gemm_kernel(
    const u16* __restrict__ ow, const float* __restrict__ Wp,
    const float* __restrict__ bp, float* __restrict__ out)
{
    __shared__ u16 As[128 * 32];
    __shared__ u16 Bs[128 * 32];
    const int tid = threadIdx.x;
    const int lane = tid & 63;
    const int wid = tid >> 6;
    const int l15 = lane & 15;
    const int quad = lane >> 4;
    const int m0 = blockIdx.x * 128;
    const int n0 = blockIdx.y * 128;

    f32x4 zero = {0.f, 0.f, 0.f, 0.f};
    f32x4 acc[4][4];
#pragma unroll
    for (int i = 0; i < 4; ++i)
#pragma unroll
        for (int j = 0; j < 4; ++j) acc[i][j] = zero;

    const int wm = (wid & 1) * 64;
    const int wn = (wid >> 1) * 64;

    const int r0 = tid >> 2;
    const int kkA = (tid & 3) * 8;
    const int r1 = r0 + 64;
    const int row4 = tid >> 3;
    const int col4 = (tid & 7) * 4;

    for (int k0 = 0; k0 < kC; k0 += 32) {
        {
            const int m = m0 + r0, b = m >> 11, t = m & 2047;
            const int kk = k0 + kkA, h = kk >> 6, d = kk & 63;
            *(short8*)&As[r0 * 32 + kkA] =
                *(const short8*)&ow[(((long)b * kH + h) * kT + t) * kD + d];
        }
        {
            const int m = m0 + r1, b = m >> 11, t = m & 2047;
            const int kk = k0 + kkA, h = kk >> 6, d = kk & 63;
            *(short8*)&As[r1 * 32 + kkA] =
                *(const short8*)&ow[(((long)b * kH + h) * kT + t) * kD + d];
        }
#pragma unroll
        for (int p = 0; p < 4; ++p) {
            const int r = p * 32 + row4;
            f32x4 wa = *(const f32x4*)&Wp[(long)(n0 + r) * kC + k0 + col4];
            short4v wsv = {(short)f2bf(wa[0]), (short)f2bf(wa[1]),
                           (short)f2bf(wa[2]), (short)f2bf(wa[3])};
            *(short4v*)&Bs[r * 32 + col4] = wsv;
        }
        __syncthreads();
        short8 af[4], bfr[4];
#pragma unroll
        for (int mt = 0; mt < 4; ++mt)
            af[mt] = *(const short8*)&As[(wm + mt * 16 + l15) * 32 + quad * 8];
#pragma unroll
        for (int nt = 0; nt < 4; ++nt)
            bfr[nt] = *(const short8*)&Bs[(wn + nt * 16 + l15) * 32 + quad * 8];
#pragma unroll
        for (int mt = 0; mt < 4; ++mt)
#pragma unroll
            for (int nt = 0; nt < 4; ++nt)
                acc[mt][nt] = MFMA16(af[mt], bfr[nt], acc[mt][nt]);
        __syncthreads();
    }

#pragma unroll
    for (int nt = 0; nt < 4; ++nt) {
        const int n = n0 + wn + nt * 16 + l15;
        const float bias_f = bp[n];
#pragma unroll
        for (int mt = 0; mt < 4; ++mt) {
#pragma unroll
            for (int r = 0; r < 4; ++r) {
                const int m = m0 + wm + mt * 16 + quad * 4 + r;
                out[(long)m * kC + n] = acc[mt][nt][r] + bias_f;
            }
        }
    }
}

// ---------------------------------------------------------------------------
extern "C" void kernel_launch(void* const* d_in, const int* in_sizes, int n_in,
                              void* d_out, int out_size, void* d_ws, size_t ws_size,
                              hipStream_t stream) {
    const float* x  = (const float*)d_in[0];
    const float* Wk = (const float*)d_in[1];
    const float* bk = (const float*)d_in[2];
    const float* Wq = (const float*)d_in[3];
    const float* bq = (const float*)d_in[4];
    const float* Wv = (const float*)d_in[5];
    const float* bv = (const float*)d_in[6];
    const float* Wp = (const float*)d_in[7];
    const float* bp = (const float*)d_in[8];
    float* out = (float*)d_out;

    u16* ws = (u16*)d_ws;
    const size_t kNeed = 72ull * 1024 * 1024;  // fast path footprint

    if (ws_size >= kNeed) {
        u16* k_ws = ws;
        u16* q_ws = ws + kQKV;
        u16* v_ws = ws + 2 * kQKV;
        u16* xb   = ws + 3 * kQKV;   // x bf16; o_ws reuses this region after qkv
        u16* o_ws = xb;
        u16* wkb  = ws + 4 * kQKV;   // wkb,wqb,wvb contiguous -> combined [3072][1024]
        u16* wqb  = wkb + (long)kC * kC;
        u16* wvb  = wqb + (long)kC * kC;
        u16* wpb  = wvb + (long)kC * kC;

        cast_kernel<<<12288, 256, 0, stream>>>(x, Wk, Wq, Wv, Wp,
                                               xb, wkb, wqb, wvb, wpb);
        qkv_gemm_bf16<<<dim3(kBT / 128, 24), 512, 0, stream>>>(
            xb, wkb, bk, bq, bv, k_ws, q_ws, v_ws);
        attn_kernel<<<1024, 256, 0, stream>>>(q_ws, k_ws, v_ws, o_ws);
        out_gemm_bf16<<<dim3(kBT / 128, kC / 128), 512, 0, stream>>>(
            o_ws, wpb, bp, out);
    } else {
        u16* k_ws = ws;
        u16* q_ws = ws + kQKV;
        u16* v_ws = ws + 2 * kQKV;
        u16* o_ws = q_ws;  // o aliases q (per-block read-then-write)

        qkv_gemm_kernel<<<dim3(kBT / 128, kC / 128, 3), 256, 0, stream>>>(
            x, Wk, bk, Wq, bq, Wv, bv, k_ws, q_ws, v_ws);
        attn_kernel<<<1024, 256, 0, stream>>>(q_ws, k_ws, v_ws, o_ws);
        out_gemm_kernel<<<dim3(kBT / 128, kC / 128), 256, 0, stream>>>(
            o_ws, Wp, bp, out);
    }
}